// Round 1
// baseline (873.221 us; speedup 1.0000x reference)
//
#include <hip/hip_runtime.h>

// Batched box-QP via ADMM (rho=1, 50 iterations), one workgroup per batch.
// M = Q + I is SPD, cond ~3. Invert in LDS via the symmetric sweep operator
// on the packed (4-padded) lower triangle, expand M^{-1} rows to registers,
// then run 50 register-resident matvec iterations.

#define NX      256
#define NITER   50
#define NQUADS  8320    // sum over rows of ceil((r+1)/4) = 33280/4
#define TRIF    33280   // padded packed-triangle floats

// offset (in floats) of padded packed row r; rows padded to 4-float multiples
__device__ __forceinline__ int rowoff(int r) {
    int M = r >> 2, s = r & 3;
    return 4 * (M + 1) * ((M << 1) + s);
}

__launch_bounds__(256, 1)
__global__ void boxqp_sweep_kernel(const float* __restrict__ Q,
                                   const float* __restrict__ p,
                                   const float* __restrict__ lb,
                                   const float* __restrict__ ub,
                                   float* __restrict__ out)
{
    extern __shared__ char smem_raw[];
    float*         tri  = (float*)smem_raw;            // 33280 f32 = 133120 B
    float*         col  = tri + TRIF;                  // 256 f32
    float*         vbuf = col + NX;                    // 256 f32
    unsigned char* qrow = (unsigned char*)(vbuf + NX); // 8320 B

    const int tid = threadIdx.x;
    const int b   = blockIdx.x;
    const size_t qbase = ((size_t)b) << 16;  // b * 256 * 256

    // --- build quad->row lookup table (one-time) ---
    {
        int bq = rowoff(tid) >> 2;
        int nq = (tid >> 2) + 1;
        for (int m = 0; m < nq; ++m) qrow[bq + m] = (unsigned char)tid;
    }
    __syncthreads();

    // --- load lower triangle of M = Q + I into padded packed LDS ---
    float4* tri4 = (float4*)tri;
    for (int s = 0; s < 33; ++s) {
        int q = tid + (s << 8);
        if (q < NQUADS) {
            int r  = qrow[q];
            int j0 = (q << 2) - rowoff(r);
            const float4 v = *(const float4*)(Q + qbase + ((size_t)r << 8) + j0);
            float4 t;
            t.x = (j0 + 0 > r) ? 0.0f : (v.x + ((j0 + 0 == r) ? 1.0f : 0.0f));
            t.y = (j0 + 1 > r) ? 0.0f : (v.y + ((j0 + 1 == r) ? 1.0f : 0.0f));
            t.z = (j0 + 2 > r) ? 0.0f : (v.z + ((j0 + 2 == r) ? 1.0f : 0.0f));
            t.w = (j0 + 3 > r) ? 0.0f : (v.w + ((j0 + 3 == r) ? 1.0f : 0.0f));
            tri4[q] = t;
        }
    }
    __syncthreads();

    // --- sweep all pivots: tri becomes -(M^{-1}) (symmetry kept throughout) ---
    for (int k = 0; k < NX; ++k) {
        // extract column k (snapshot, pre-update values)
        {
            int addr = (tid >= k) ? (rowoff(tid) + k) : (rowoff(k) + tid);
            col[tid] = tri[addr];
        }
        __syncthreads();
        const float invd = 1.0f / col[k];

        // rank-1 update of the whole padded triangle:
        // a[i][j] -= col[i]*col[j]*invd  (row k / col k get fixed after)
        for (int s = 0; s < 33; ++s) {
            int q = tid + (s << 8);
            if (q < NQUADS) {
                int r  = qrow[q];
                int j0 = (q << 2) - rowoff(r);
                float cr = col[r] * invd;
                const float4 c4 = *(const float4*)(col + j0);
                float4 t = tri4[q];
                t.x -= cr * c4.x;
                t.y -= cr * c4.y;
                t.z -= cr * c4.z;
                t.w -= cr * c4.w;
                tri4[q] = t;
            }
        }
        __syncthreads();

        // fix column k: a[i][k] = col[i]/d (i != k), a[k][k] = -1/d
        {
            int addr = (tid >= k) ? (rowoff(tid) + k) : (rowoff(k) + tid);
            tri[addr] = (tid == k) ? (-invd) : (col[tid] * invd);
        }
        __syncthreads();
    }

    // --- expand row `tid` of swept matrix (= -M^{-1}) into registers ---
    float mrow[NX];
    {
        const int offi = rowoff(tid);
        #pragma unroll
        for (int j = 0; j < NX; ++j) {
            int addr = (j <= tid) ? (offi + j) : (rowoff(j) + tid); // rowoff(j) folds
            mrow[j] = tri[addr];
        }
    }

    const int base  = (b << 8) + tid;
    const float pi  = p[base];
    const float lbi = lb[base];
    const float ubi = ub[base];

    // --- 50 ADMM iterations, matrix in registers, rhs broadcast via LDS ---
    // vbuf = -(rhs) = u + p - z ;  x = (-Minv) dot vbuf = Minv * rhs
    float x = 0.0f, z = 0.0f, u = 0.0f;
    __syncthreads();
    for (int it = 0; it < NITER; ++it) {
        vbuf[tid] = (u + pi) - z;
        __syncthreads();
        float a0 = 0.f, a1 = 0.f, a2 = 0.f, a3 = 0.f;
        #pragma unroll
        for (int j = 0; j < NX; j += 4) {
            a0 += mrow[j + 0] * vbuf[j + 0];
            a1 += mrow[j + 1] * vbuf[j + 1];
            a2 += mrow[j + 2] * vbuf[j + 2];
            a3 += mrow[j + 3] * vbuf[j + 3];
        }
        x = (a0 + a1) + (a2 + a3);
        const float xu = x + u;
        z = fminf(fmaxf(xu, lbi), ubi);
        u = xu - z;
        __syncthreads();
    }

    out[base] = x;
}

extern "C" void kernel_launch(void* const* d_in, const int* in_sizes, int n_in,
                              void* d_out, int out_size, void* d_ws, size_t ws_size,
                              hipStream_t stream) {
    const float* Q  = (const float*)d_in[0];
    const float* p  = (const float*)d_in[1];
    const float* lb = (const float*)d_in[2];
    const float* ub = (const float*)d_in[3];
    float* out = (float*)d_out;

    const size_t shmem = (size_t)TRIF * 4 + NX * 4 + NX * 4 + NQUADS; // 143488 B
    // opt in to >64KB dynamic LDS (idempotent; not a stream op, capture-safe)
    (void)hipFuncSetAttribute((const void*)boxqp_sweep_kernel,
                              hipFuncAttributeMaxDynamicSharedMemorySize,
                              (int)shmem);

    hipLaunchKernelGGL(boxqp_sweep_kernel, dim3(256), dim3(256), shmem, stream,
                       Q, p, lb, ub, out);
}

// Round 2
// 362.005 us; speedup vs baseline: 2.4122x; 2.4122x over previous
//
#include <hip/hip_runtime.h>

// Batched box-QP via ADMM (rho=1, 50 iters), one 1024-thread workgroup per batch.
// M = Q + I (SPD, cond~3) inverted in LDS by a RANK-4 BLOCKED symmetric sweep
// on the packed (quad-padded) lower triangle. 4x4 register tiles for the
// Schur update. Iterations: 4 threads/row, 64-float register chunks,
// shfl_xor reduce, rhs broadcast from padded LDS chunks.

#define NX     256
#define NITER  50
#define TRIF   33280   // padded packed-triangle floats
#define NTILE  2080    // 4x4 tiles in 64x64 block-triangle
#define NTHR   1024

// offset (floats) of padded packed row r (rows padded to 4-float quads)
__device__ __forceinline__ int rowoff(int r) {
    int M = r >> 2, s = r & 3;
    return 4 * (M + 1) * ((M << 1) + s);
}

__launch_bounds__(NTHR, 1)
__global__ void boxqp_blk_kernel(const float* __restrict__ Q,
                                 const float* __restrict__ p,
                                 const float* __restrict__ lb,
                                 const float* __restrict__ ub,
                                 float* __restrict__ out)
{
    extern __shared__ char smem_raw[];
    float*  tri  = (float*)smem_raw;                 // 33280 f = 133120 B
    float4* tri4 = (float4*)tri;
    float4* P4   = (float4*)(tri + TRIF);            // 256 f4 = 4096 B
    float4* W4   = P4 + NX;                          // 256 f4 = 4096 B
    float*  vbuf = (float*)(W4 + NX);                // 272 f  = 1088 B (4 chunks of 68)
    unsigned char* lut = (unsigned char*)(vbuf + 272); // 2080 B tile->rowblock

    const int t = threadIdx.x;
    const int b = blockIdx.x;
    const size_t qbase = ((size_t)b) << 16;          // b*256*256

    // --- tile -> row-block LUT ---
    if (t < 64) {
        int base = (t * (t + 1)) >> 1;
        for (int c = 0; c <= t; ++c) lut[base + c] = (unsigned char)t;
    }
    __syncthreads();

    // --- load lower triangle of M = Q + I, tile by tile ---
    for (int tile = t; tile < NTILE; tile += NTHR) {
        int rb = lut[tile];
        int cb = tile - ((rb * (rb + 1)) >> 1);
        int r0 = rb << 2, j0 = cb << 2;
        int q0 = ((rb + 1) * (rb << 1)) + cb, step = rb + 1;
        if (rb != cb) {
            #pragma unroll
            for (int s2 = 0; s2 < 4; ++s2) {
                float4 v = *(const float4*)(Q + qbase + (size_t)(r0 + s2) * NX + j0);
                tri4[q0 + s2 * step] = v;
            }
        } else {
            #pragma unroll
            for (int s2 = 0; s2 < 4; ++s2) {
                int rr = r0 + s2;
                float4 v = *(const float4*)(Q + qbase + (size_t)rr * NX + j0);
                float4 tq;
                tq.x = (j0 + 0 > rr) ? 0.f : (v.x + ((j0 + 0 == rr) ? 1.f : 0.f));
                tq.y = (j0 + 1 > rr) ? 0.f : (v.y + ((j0 + 1 == rr) ? 1.f : 0.f));
                tq.z = (j0 + 2 > rr) ? 0.f : (v.z + ((j0 + 2 == rr) ? 1.f : 0.f));
                tq.w = (j0 + 3 > rr) ? 0.f : (v.w + ((j0 + 3 == rr) ? 1.f : 0.f));
                tri4[q0 + s2 * step] = tq;
            }
        }
    }
    __syncthreads();

    // --- rank-4 blocked sweep: 64 block steps; tri becomes -(M^{-1}) ---
    for (int kb = 0; kb < 64; ++kb) {
        const int k0 = kb << 2;

        // phase 1: snapshot panel P[i][0..3] = A[i][k0..k0+3]
        if (t < NX) {
            int i = t;
            float4 pv;
            if (i >= k0 + 4) {
                pv = tri4[(rowoff(i) >> 2) + kb];
            } else {
                float v0, v1, v2, v3;
                #pragma unroll
                for (int m = 0; m < 4; ++m) {
                    int km = k0 + m;
                    float vv = (km <= i) ? tri[rowoff(i) + km] : tri[rowoff(km) + i];
                    if (m == 0) v0 = vv; else if (m == 1) v1 = vv;
                    else if (m == 2) v2 = vv; else v3 = vv;
                }
                pv = make_float4(v0, v1, v2, v3);
            }
            P4[i] = pv;
        }
        __syncthreads();

        // phase 2: S = -D^{-1} (every thread, redundant, from LDS broadcast);
        //          W[i] = P[i] * D^{-1} = -(P[i] * S)  (threads < 256)
        float S[4][4];
        {
            #pragma unroll
            for (int m = 0; m < 4; ++m) {
                float4 pr = P4[k0 + m];
                S[m][0] = pr.x; S[m][1] = pr.y; S[m][2] = pr.z; S[m][3] = pr.w;
            }
            #pragma unroll
            for (int kk = 0; kk < 4; ++kk) {
                float inv = 1.0f / S[kk][kk];
                #pragma unroll
                for (int a2 = 0; a2 < 4; ++a2) {
                    if (a2 == kk) continue;
                    #pragma unroll
                    for (int b2 = 0; b2 < 4; ++b2) {
                        if (b2 == kk) continue;
                        S[a2][b2] -= S[a2][kk] * S[kk][b2] * inv;
                    }
                }
                #pragma unroll
                for (int a2 = 0; a2 < 4; ++a2) {
                    if (a2 == kk) continue;
                    S[a2][kk] *= inv;
                    S[kk][a2] *= inv;
                }
                S[kk][kk] = -inv;
            }
        }
        if (t < NX) {
            float4 pr = P4[t];
            float4 w;
            w.x = -(pr.x * S[0][0] + pr.y * S[1][0] + pr.z * S[2][0] + pr.w * S[3][0]);
            w.y = -(pr.x * S[0][1] + pr.y * S[1][1] + pr.z * S[2][1] + pr.w * S[3][1]);
            w.z = -(pr.x * S[0][2] + pr.y * S[1][2] + pr.z * S[2][2] + pr.w * S[3][2]);
            w.w = -(pr.x * S[0][3] + pr.y * S[1][3] + pr.z * S[2][3] + pr.w * S[3][3]);
            W4[t] = w;
        }
        __syncthreads();

        // phase 3: rank-4 update of all tiles + pivot row/col/block fixes
        for (int tile = t; tile < NTILE; tile += NTHR) {
            int rb = lut[tile];
            int cb = tile - ((rb * (rb + 1)) >> 1);
            int r0 = rb << 2;
            int q0 = ((rb + 1) * (rb << 1)) + cb, step = rb + 1;
            if (rb == kb) {
                if (cb == kb) {           // pivot block: A[K,K] = -D^{-1} = S
                    #pragma unroll
                    for (int s2 = 0; s2 < 4; ++s2)
                        tri4[q0 + s2 * step] = make_float4(S[s2][0], S[s2][1], S[s2][2], S[s2][3]);
                } else {                  // pivot rows: A[K,j] = W[j][s] (symmetry)
                    int j0 = cb << 2;
                    #pragma unroll
                    for (int s2 = 0; s2 < 4; ++s2) {
                        float4 v;
                        v.x = ((const float*)(W4 + j0 + 0))[s2];
                        v.y = ((const float*)(W4 + j0 + 1))[s2];
                        v.z = ((const float*)(W4 + j0 + 2))[s2];
                        v.w = ((const float*)(W4 + j0 + 3))[s2];
                        tri4[q0 + s2 * step] = v;
                    }
                }
            } else if (cb == kb) {        // panel: A[r,K] = W[r]
                #pragma unroll
                for (int s2 = 0; s2 < 4; ++s2)
                    tri4[q0 + s2 * step] = W4[r0 + s2];
            } else {                      // Schur: A -= W * P^T
                int j0 = cb << 2;
                float4 Pc0 = P4[j0 + 0], Pc1 = P4[j0 + 1], Pc2 = P4[j0 + 2], Pc3 = P4[j0 + 3];
                #pragma unroll
                for (int s2 = 0; s2 < 4; ++s2) {
                    float4 wr = W4[r0 + s2];
                    float4 tq = tri4[q0 + s2 * step];
                    tq.x -= wr.x * Pc0.x + wr.y * Pc0.y + wr.z * Pc0.z + wr.w * Pc0.w;
                    tq.y -= wr.x * Pc1.x + wr.y * Pc1.y + wr.z * Pc1.z + wr.w * Pc1.w;
                    tq.z -= wr.x * Pc2.x + wr.y * Pc2.y + wr.z * Pc2.z + wr.w * Pc2.w;
                    tq.w -= wr.x * Pc3.x + wr.y * Pc3.y + wr.z * Pc3.z + wr.w * Pc3.w;
                    tri4[q0 + s2 * step] = tq;
                }
            }
        }
        __syncthreads();
    }

    // --- expand: thread (r, q4) holds Minv-row chunk j in [64*q4, 64*q4+64) ---
    const int r  = t >> 2;
    const int q4 = t & 3;
    const int jc = q4 << 6;
    float mr[64];
    {
        const int offr = rowoff(r);
        #pragma unroll
        for (int jj = 0; jj < 64; ++jj) {
            int j = jc + jj;
            int addr = (j <= r) ? (offr + j) : (rowoff(j) + r);
            mr[jj] = tri[addr];   // = -Minv[r][j]
        }
    }

    const int gb = (b << 8) + r;
    const float pi = p[gb], lbi = lb[gb], ubi = ub[gb];
    const int vw = r + ((r >> 6) << 2);   // padded rhs slot (stride-68 chunks)

    float x = 0.f, z = 0.f, u = 0.f;
    __syncthreads();
    for (int it = 0; it < NITER; ++it) {
        if (q4 == 0) vbuf[vw] = (u + pi) - z;   // vbuf = -(rhs)
        __syncthreads();
        const float4* vb4 = (const float4*)(vbuf + q4 * 68);
        float a0 = 0.f, a1 = 0.f, a2 = 0.f, a3 = 0.f;
        #pragma unroll
        for (int m = 0; m < 16; ++m) {
            float4 v = vb4[m];
            a0 += mr[4 * m + 0] * v.x;
            a1 += mr[4 * m + 1] * v.y;
            a2 += mr[4 * m + 2] * v.z;
            a3 += mr[4 * m + 3] * v.w;
        }
        float s = (a0 + a1) + (a2 + a3);
        s += __shfl_xor(s, 1);
        s += __shfl_xor(s, 2);
        x = s;                                   // x = Minv * rhs
        float xu = x + u;
        z = fminf(fmaxf(xu, lbi), ubi);
        u = xu - z;
        __syncthreads();
    }

    if (q4 == 0) out[gb] = x;
}

extern "C" void kernel_launch(void* const* d_in, const int* in_sizes, int n_in,
                              void* d_out, int out_size, void* d_ws, size_t ws_size,
                              hipStream_t stream) {
    const float* Q  = (const float*)d_in[0];
    const float* p  = (const float*)d_in[1];
    const float* lb = (const float*)d_in[2];
    const float* ub = (const float*)d_in[3];
    float* out = (float*)d_out;

    const size_t shmem = (size_t)TRIF * 4 + NX * 16 + NX * 16 + 272 * 4 + NTILE; // 144480 B
    (void)hipFuncSetAttribute((const void*)boxqp_blk_kernel,
                              hipFuncAttributeMaxDynamicSharedMemorySize,
                              (int)shmem);

    hipLaunchKernelGGL(boxqp_blk_kernel, dim3(256), dim3(NTHR), shmem, stream,
                       Q, p, lb, ub, out);
}